// Round 12
// baseline (86.475 us; speedup 1.0000x reference)
//
#include <hip/hip_runtime.h>
#include <hip/hip_bf16.h>

#define HH 200
#define WW 176
#define CIN 256
#define CO 28
#define BN_EPS 1e-3f

typedef __attribute__((ext_vector_type(8))) short short8;
typedef __attribute__((ext_vector_type(4))) float f32x4;

static __device__ __forceinline__ ushort f2bf(float f) {
    __hip_bfloat16 h = __float2bfloat16(f);
    return __builtin_bit_cast(ushort, h);
}

// ---------------------------------------------------------------------------
// prep: w1b chunk-major [h][t][n][lane][j] (bf16, BN-folded), plus shift[28].
//   co = n*16 + (lane&15), ci = h*32 + (lane>>4)*8 + j
// ---------------------------------------------------------------------------
__global__ void prep_k(const float* __restrict__ w1, const float* __restrict__ gamma,
                       const float* __restrict__ beta, const float* __restrict__ mean,
                       const float* __restrict__ var, ushort* __restrict__ w1b,
                       float* __restrict__ shift)
{
    int idx = blockIdx.x * 256 + threadIdx.x;
    if (idx < CO) {
        float sc = gamma[idx] * rsqrtf(var[idx] + BN_EPS);
        shift[idx] = beta[idx] - mean[idx] * sc;
    }
    if (idx < 8 * 9 * 2 * 64 * 8) {
        int j   = idx & 7;
        int l   = (idx >> 3) & 63;
        int n   = (idx >> 9) & 1;
        int rem = idx >> 10;          // h*9 + t
        int t   = rem % 9;
        int h   = rem / 9;
        int co = n * 16 + (l & 15);
        int ci = h * 32 + (l >> 4) * 8 + j;
        float v = 0.f;
        if (co < CO) {
            float sc = gamma[co] * rsqrtf(var[co] + BN_EPS);
            v = w1[(co * CIN + ci) * 9 + t] * sc;
        }
        w1b[idx] = f2bf(v);
    }
}

// ---------------------------------------------------------------------------
// Implicit-GEMM conv3x3 + BN + ReLU, FULL-ROW tiles (176 x 4 rows).
// Row staging reads are exactly 11 aligned 64B lines (100% line efficiency;
// x-halo columns are image borders -> zero-filled LDS once). Block = 512 thr
// (8 waves); waves 0-2 own 2 M-frags (16px each), 3-7 own 1 (11 frags).
// LDS A: [buf][oct][row6][px180] x 16B -> ds_read_b128 over consecutive px is
// contiguous = conflict-free, no swizzle. All hot VMEM = volatile asm with
// counted vmcnt (loads clamped, never skipped -> wave-uniform counts).
// One barrier per chunk, double-buffered.
// ---------------------------------------------------------------------------
__global__ __launch_bounds__(512, 1) void conv_mfma_k(
    const float* __restrict__ x, const ushort* __restrict__ w1b,
    const float* __restrict__ shift, float* __restrict__ y1)
{
    __shared__ ushort sA[2][4][6][180][8];   // 138240 B

    const int tid  = threadIdx.x;
    const int lane = tid & 63;
    const int w    = tid >> 6;               // wave 0..7
    const int c_   = lane & 15;
    const int oct  = lane >> 4;

    // XCD swizzle: 200 blocks, 200%8==0 -> simple bijective chunking
    const int bid  = blockIdx.x;
    const int tile = (bid & 7) * 25 + (bid >> 3);
    const int ty   = tile % 50;
    const int b    = tile / 50;
    const int y0   = ty * 4;

    const float* xb = x + (size_t)b * CIN * HH * WW;

    // staging map: 2112 groups = 6 rows x 44 quads x 8 ci-quads; 5/thread
    // (s mod 2112 -> last 448 redundant rewrites, keeps vmcnt wave-uniform)
    uint voffb[5]; bool gval[5]; int gr[5], gq[5], gcq[5];
#pragma unroll
    for (int i = 0; i < 5; ++i) {
        int s  = (i * 512 + tid) % 2112;
        int r  = s / 352;                    // 352 = 44*8
        int rm = s % 352;
        int q  = rm >> 3;
        int cq = rm & 7;
        int gy = y0 + r - 1;
        bool v = (gy >= 0) && (gy < HH);
        int gyc = v ? gy : 0;
        gval[i] = v; gr[i] = r; gq[i] = q; gcq[i] = cq;
        voffb[i] = (uint)(((cq * 4) * (HH * WW) + gyc * WW + q * 4) * 4);
    }
    const uint wvoff = (uint)(lane * 16);

    f32x4  sreg[5][4];
    short8 wqA[6], wqB[6];
    f32x4  acc[2][4][2];
#pragma unroll
    for (int s = 0; s < 2; ++s)
#pragma unroll
        for (int r = 0; r < 4; ++r)
#pragma unroll
            for (int n = 0; n < 2; ++n)
                acc[s][r][n] = (f32x4){0.f, 0.f, 0.f, 0.f};

#define SB __builtin_amdgcn_sched_barrier(0)
#define VWAIT(N) asm volatile("s_waitcnt vmcnt(" #N ")" ::: "memory")
#define KEEPW(WQ)                                                             \
    asm volatile("" : "+v"(WQ[0]), "+v"(WQ[1]), "+v"(WQ[2]), "+v"(WQ[3]),     \
                      "+v"(WQ[4]), "+v"(WQ[5]))
#define KEEPS                                                                 \
    asm volatile("" : "+v"(sreg[0][0]), "+v"(sreg[0][1]), "+v"(sreg[0][2]),   \
        "+v"(sreg[0][3]), "+v"(sreg[1][0]), "+v"(sreg[1][1]),                 \
        "+v"(sreg[1][2]), "+v"(sreg[1][3]), "+v"(sreg[2][0]),                 \
        "+v"(sreg[2][1]));                                                    \
    asm volatile("" : "+v"(sreg[2][2]), "+v"(sreg[2][3]), "+v"(sreg[3][0]),   \
        "+v"(sreg[3][1]), "+v"(sreg[3][2]), "+v"(sreg[3][3]),                 \
        "+v"(sreg[4][0]), "+v"(sreg[4][1]), "+v"(sreg[4][2]),                 \
        "+v"(sreg[4][3]))

// issue 20 x quad-loads for chunk hn (whole halo strip, 4 px x 4 ci each)
#define STAGEISS(hn)                                                          \
    {                                                                         \
        _Pragma("unroll")                                                     \
        for (int i = 0; i < 5; ++i) {                                         \
            _Pragma("unroll")                                                 \
            for (int j = 0; j < 4; ++j) {                                     \
                uint vo = voffb[i] + (uint)(((hn) * 32 + j) * (HH * WW * 4)); \
                asm volatile("global_load_dwordx4 %0, %1, %2"                 \
                             : "=v"(sreg[i][j]) : "v"(vo), "s"(xb));          \
            }                                                                 \
        }                                                                     \
    }

// 6 weight-frag loads for tap-column dx of chunk h
#define WLOAD6(h, dx, WQ)                                                     \
    {                                                                         \
        _Pragma("unroll")                                                     \
        for (int dy = 0; dy < 3; ++dy) {                                      \
            _Pragma("unroll")                                                 \
            for (int n = 0; n < 2; ++n) {                                     \
                const ushort* bk = w1b + (size_t)(h) * 9216                   \
                                 + (size_t)((dy * 3 + (dx)) * 2 + n) * 512;   \
                asm volatile("global_load_dwordx4 %0, %1, %2"                 \
                             : "=v"(WQ[dy * 2 + n]) : "v"(wvoff), "s"(bk));   \
            }                                                                 \
        }                                                                     \
    }

// convert + pack staged regs into buffer BUFI ([oct][r][pp] layout)
#define PACK(BUFI)                                                            \
    {                                                                         \
        _Pragma("unroll")                                                     \
        for (int i = 0; i < 5; ++i) {                                         \
            _Pragma("unroll")                                                 \
            for (int k = 0; k < 4; ++k) {                                     \
                ushort u[4];                                                  \
                _Pragma("unroll")                                             \
                for (int j = 0; j < 4; ++j)                                   \
                    u[j] = gval[i] ? f2bf(sreg[i][j][k]) : (ushort)0;         \
                uint2 val;                                                    \
                val.x = (uint)u[0] | ((uint)u[1] << 16);                      \
                val.y = (uint)u[2] | ((uint)u[3] << 16);                      \
                *(uint2*)&sA[BUFI][gcq[i] >> 1][gr[i]][gq[i] * 4 + k + 1]     \
                            [(gcq[i] & 1) * 4] = val;                         \
            }                                                                 \
        }                                                                     \
    }

// A-reads + MFMA for tap-column dx (heavy waves do 2 M-frags)
#define COMP_DX(dx, WQ, BUFI)                                                 \
    {                                                                         \
        _Pragma("unroll")                                                     \
        for (int s = 0; s < 2; ++s) {                                         \
            const int mf = w + 8 * s;                                         \
            if (mf < 11) {                                                    \
                short8 av[6];                                                 \
                _Pragma("unroll")                                             \
                for (int r = 0; r < 6; ++r)                                   \
                    av[r] = *(const short8*)&sA[BUFI][oct][r]                 \
                                [16 * mf + c_ + (dx)][0];                     \
                _Pragma("unroll")                                             \
                for (int dy = 0; dy < 3; ++dy) {                              \
                    _Pragma("unroll")                                         \
                    for (int r = 0; r < 4; ++r) {                             \
                        acc[s][r][0] = __builtin_amdgcn_mfma_f32_16x16x32_bf16( \
                            av[r + dy], WQ[dy * 2 + 0], acc[s][r][0], 0, 0, 0);  \
                        acc[s][r][1] = __builtin_amdgcn_mfma_f32_16x16x32_bf16( \
                            av[r + dy], WQ[dy * 2 + 1], acc[s][r][1], 0, 0, 0);  \
                    }                                                         \
                }                                                             \
            }                                                                 \
        }                                                                     \
    }

#define BODY(h)                                                               \
    {                                                                         \
        WLOAD6(h, 0, wqA); WLOAD6(h, 1, wqB); STAGEISS((h) + 1);              \
        VWAIT(26); KEEPW(wqA); SB; COMP_DX(0, wqA, (h) & 1);                  \
        WLOAD6(h, 2, wqA);                                                    \
        VWAIT(26); KEEPW(wqB); SB; COMP_DX(1, wqB, (h) & 1);                  \
        VWAIT(0); KEEPW(wqA); KEEPS; SB; COMP_DX(2, wqA, (h) & 1);            \
        PACK(((h) + 1) & 1);                                                  \
        __syncthreads();                                                      \
    }

    // zero border columns pp=0 and pp=177 (both buffers), once
    if (tid < 96) {
        int bufb = tid / 48, rm = tid % 48;
        int o = rm / 12, r2 = (rm % 12) / 2, side = rm & 1;
        *(short8*)&sA[bufb][o][r2][side ? 177 : 0][0] = (short8){0,0,0,0,0,0,0,0};
    }

    // prologue: stage chunk 0
    STAGEISS(0);
    VWAIT(0); KEEPS; SB;
    PACK(0);
    __syncthreads();

    BODY(0) BODY(1) BODY(2) BODY(3) BODY(4) BODY(5) BODY(6)

    // last chunk: no staging
    {
        WLOAD6(7, 0, wqA); WLOAD6(7, 1, wqB);
        VWAIT(6); KEEPW(wqA); SB; COMP_DX(0, wqA, 1);
        WLOAD6(7, 2, wqA);
        VWAIT(6); KEEPW(wqB); SB; COMP_DX(1, wqB, 1);
        VWAIT(0); KEEPW(wqA); SB; COMP_DX(2, wqA, 1);
    }

    // epilogue: + shift, ReLU, store channel-last y1
    const float s0 = shift[c_];
    const float s1 = (16 + c_ < CO) ? shift[16 + c_] : 0.f;
#pragma unroll
    for (int s = 0; s < 2; ++s) {
        const int mf = w + 8 * s;
        if (mf < 11) {
#pragma unroll
            for (int r = 0; r < 4; ++r) {
                int gy = y0 + r;
#pragma unroll
                for (int reg = 0; reg < 4; ++reg) {
                    int gx = 16 * mf + oct * 4 + reg;
                    float* yp = y1 + ((size_t)(b * HH + gy) * WW + gx) * CO;
                    float v0 = acc[s][r][0][reg] + s0;
                    yp[c_] = v0 > 0.f ? v0 : 0.f;
                    if (16 + c_ < CO) {
                        float v1 = acc[s][r][1][reg] + s1;
                        yp[16 + c_] = v1 > 0.f ? v1 : 0.f;
                    }
                }
            }
        }
    }
}

// ---------------------------------------------------------------------------
// Sampler: thread = (box, k).  Bilinear sample of conv1x1 output = conv1x1 of
// bilinear samples (linear, bias-free).  Mean over k via LDS reduce.
// ---------------------------------------------------------------------------
__global__ __launch_bounds__(224) void sample_k(
    const float* __restrict__ y1, const float* __restrict__ ga,
    const float* __restrict__ w2, float* __restrict__ out)
{
    __shared__ float red[224];
    const int lb  = threadIdx.x / CO;   // local box 0..7
    const int k   = threadIdx.x % CO;   // window index / channel
    const int box = blockIdx.x * 8 + lb;
    const int b   = box >> 11;          // / 2048

    const float* ap = ga + (size_t)box * 7;
    float xg = ap[0], yg = ap[1], wg = ap[3], lg = ap[4], rg = ap[6];
    float c = cosf(rg), s = sinf(rg);

    const int i = k / 7, j = k % 7;
    float xx = ((float)i * (1.f / 3.f) - 0.5f) * wg;
    float yy = ((float)j * (1.f / 6.f) - 0.5f) * lg;
    float xs = (xx * c + yy * s + xg) * 2.5f;
    float ys = (yy * c - xx * s + yg + 40.f) * 2.5f;

    float x0 = floorf(xs), y0 = floorf(ys);
    float wx = xs - x0,    wy = ys - y0;

    float w2r[CO];
    const float* w2p = w2 + k * CO;
#pragma unroll
    for (int q = 0; q < 7; ++q) {
        float4 t = ((const float4*)w2p)[q];
        w2r[4*q] = t.x; w2r[4*q+1] = t.y; w2r[4*q+2] = t.z; w2r[4*q+3] = t.w;
    }

    float val = 0.f;
    const float* yb = y1 + (size_t)b * HH * WW * CO;
#pragma unroll
    for (int cor = 0; cor < 4; ++cor) {
        float yf = y0 + (float)(cor >> 1);
        float xf = x0 + (float)(cor & 1);
        float cw = ((cor & 1) ? wx : 1.f - wx) * ((cor >> 1) ? wy : 1.f - wy);
        if (yf >= 0.f && yf <= (float)(HH - 1) && xf >= 0.f && xf <= (float)(WW - 1)) {
            int yi = (int)yf, xi = (int)xf;
            const float* p = yb + ((size_t)yi * WW + xi) * CO;
            float d = 0.f;
#pragma unroll
            for (int q = 0; q < 7; ++q) {
                float4 t = ((const float4*)p)[q];
                d = fmaf(w2r[4*q],   t.x, d);
                d = fmaf(w2r[4*q+1], t.y, d);
                d = fmaf(w2r[4*q+2], t.z, d);
                d = fmaf(w2r[4*q+3], t.w, d);
            }
            val = fmaf(cw, d, val);
        }
    }

    red[threadIdx.x] = val;
    __syncthreads();
    if (k == 0) {
        float sum = 0.f;
#pragma unroll
        for (int q = 0; q < CO; ++q) sum += red[lb * CO + q];
        out[box] = sum * (1.f / 28.f);
    }
}

// ---------------------------------------------------------------------------
extern "C" void kernel_launch(void* const* d_in, const int* in_sizes, int n_in,
                              void* d_out, int out_size, void* d_ws, size_t ws_size,
                              hipStream_t stream) {
    const float* x     = (const float*)d_in[0];
    const float* ga    = (const float*)d_in[1];
    const float* w1    = (const float*)d_in[2];
    const float* gamma = (const float*)d_in[3];
    const float* beta  = (const float*)d_in[4];
    const float* mean  = (const float*)d_in[5];
    const float* var   = (const float*)d_in[6];
    const float* w2    = (const float*)d_in[7];
    float* out = (float*)d_out;

    ushort* w1b   = (ushort*)d_ws;                         // 147456 B
    float*  shift = (float*)((char*)d_ws + 147456);        // 112 B
    float*  y1    = (float*)((char*)d_ws + 147968);        // 4*200*176*28 f32

    prep_k<<<(8 * 9 * 2 * 64 * 8 + 255) / 256, 256, 0, stream>>>(
        w1, gamma, beta, mean, var, w1b, shift);

    conv_mfma_k<<<50 * 4, 512, 0, stream>>>(x, w1b, shift, y1);

    sample_k<<<(4 * 2048) / 8, 224, 0, stream>>>(y1, ga, w2, out);
}

// Round 14
// 84.496 us; speedup vs baseline: 1.0234x; 1.0234x over previous
//
#include <hip/hip_runtime.h>
#include <hip/hip_bf16.h>

#define HH 200
#define WW 176
#define CIN 256
#define CO 28
#define BN_EPS 1e-3f

typedef __attribute__((ext_vector_type(8))) short short8;
typedef __attribute__((ext_vector_type(4))) float f32x4;

static __device__ __forceinline__ ushort f2bf(float f) {
    __hip_bfloat16 h = __float2bfloat16(f);
    return __builtin_bit_cast(ushort, h);
}

// ---------------------------------------------------------------------------
// prep: w1b chunk-major [h][t][n][lane][j] (bf16, BN-folded), plus shift[28].
//   co = n*16 + (lane&15), ci = h*32 + (lane>>4)*8 + j
// ---------------------------------------------------------------------------
__global__ void prep_k(const float* __restrict__ w1, const float* __restrict__ gamma,
                       const float* __restrict__ beta, const float* __restrict__ mean,
                       const float* __restrict__ var, ushort* __restrict__ w1b,
                       float* __restrict__ shift)
{
    int idx = blockIdx.x * 256 + threadIdx.x;
    if (idx < CO) {
        float sc = gamma[idx] * rsqrtf(var[idx] + BN_EPS);
        shift[idx] = beta[idx] - mean[idx] * sc;
    }
    if (idx < 8 * 9 * 2 * 64 * 8) {
        int j   = idx & 7;
        int l   = (idx >> 3) & 63;
        int n   = (idx >> 9) & 1;
        int rem = idx >> 10;          // h*9 + t
        int t   = rem % 9;
        int h   = rem / 9;
        int co = n * 16 + (l & 15);
        int ci = h * 32 + (l >> 4) * 8 + j;
        float v = 0.f;
        if (co < CO) {
            float sc = gamma[co] * rsqrtf(var[co] + BN_EPS);
            v = w1[(co * CIN + ci) * 9 + t] * sc;
        }
        w1b[idx] = f2bf(v);
    }
}

// ---------------------------------------------------------------------------
// Implicit-GEMM conv3x3 + BN + ReLU, ci-split free-running waves.
// Tile 16x8 px; wave w owns LDS buffer w and ci-chunks {w, w+4} end-to-end;
// NO barriers until the final 2-barrier reduction. Staging: lane owns
// ci = oct*8+jl; quads qu = 2i + parity(lane), i in [0,30), over a 6-quad
// ALIGNED window [x0-4, x0+20) per row (all loads 16B-aligned; clamped edge
// quads are fully invalid -> plain masks, no shifts). 3 ping-pong batches of
// 10 dwordx4 keep peak staging regs at 80. W-frags in 6-load dx lookahead.
// All waits are counted vmcnt with dest regs carried as "+v".
// ---------------------------------------------------------------------------
__global__ __launch_bounds__(256, 2) void conv_mfma_k(
    const float* __restrict__ x, const ushort* __restrict__ w1b,
    const float* __restrict__ shift, float* __restrict__ y1)
{
    __shared__ ushort sA[4][9600];        // 240 px-slots x 40 ushorts, per wave

    const int tid  = threadIdx.x;
    const int lane = tid & 63;
    const int w    = tid >> 6;
    const int wu   = __builtin_amdgcn_readfirstlane(w);
    const int c_   = lane & 15;
    const int oct  = lane >> 4;
    const int jl   = lane & 7;
    const int p    = (lane >> 3) & 1;
    const int ci   = oct * 8 + jl;

    // XCD-aware bijective block swizzle (1100 blocks, 8 XCDs)
    const int NB = 11 * 25 * 4;
    const int q = NB / 8, r = NB % 8;     // 137, 4
    const int bid  = blockIdx.x;
    const int xcd  = bid & 7;
    const int rank = bid >> 3;
    const int tile = (xcd < r ? xcd * (q + 1) : r * (q + 1) + (xcd - r) * q) + rank;

    const int tx  = tile % 11;
    const int rem = tile / 11;
    const int ty  = rem % 25;
    const int b   = rem / 25;
    const int x0  = tx * 16, y0 = ty * 8;

    const char* xbb = (const char*)(x + (size_t)b * CIN * HH * WW);
    const uint wvoff = (uint)(lane * 16);

    // per-lane staging geometry helpers (i literal after unroll)
    auto geovoff = [&](int i) -> uint {
        int qu  = 2 * i + p;
        int row = qu / 6, qc = qu - row * 6;
        int gy  = y0 + row - 1;
        int gyc = gy < 0 ? 0 : (gy > HH - 1 ? HH - 1 : gy);
        int gx0 = x0 - 4 + qc * 4;
        int gx0c = gx0 < 0 ? 0 : (gx0 > WW - 4 ? WW - 4 : gx0);
        return (uint)((ci * (HH * WW) + gyc * WW + gx0c) * 4);
    };
    auto packone = [&](int i, f32x4 v) {
        int qu  = 2 * i + p;
        int row = qu / 6, qc = qu - row * 6;
        int gy  = y0 + row - 1;
        bool yv = (gy >= 0) & (gy < HH);
        int gx0 = x0 - 4 + qc * 4;
        ushort* dst = &sA[w][(qu * 4) * 40 + ci];
#pragma unroll
        for (int k = 0; k < 4; ++k) {
            bool valid = yv & (gx0 + k >= 0) & (gx0 + k < WW);
            dst[k * 40] = valid ? f2bf(v[k]) : (ushort)0;
        }
    };

    f32x4  sa[10], sb[10], sc[10];
    short8 wqA[6], wqB[6];
    f32x4  acc[8][2];
#pragma unroll
    for (int m = 0; m < 8; ++m)
#pragma unroll
        for (int n = 0; n < 2; ++n)
            acc[m][n] = (f32x4){0.f, 0.f, 0.f, 0.f};

#define SBAR __builtin_amdgcn_sched_barrier(0)

#define XISS(ch, SET, I0)                                                     \
    {                                                                         \
        const char* bj = xbb + (size_t)(ch) * 4505600;                        \
        _Pragma("unroll")                                                     \
        for (int i = 0; i < 10; ++i) {                                        \
            uint vo = geovoff(i + (I0));                                      \
            asm volatile("global_load_dwordx4 %0, %1, %2"                     \
                         : "=v"(SET[i]) : "v"(vo), "s"(bj));                  \
        }                                                                     \
    }

#define VWX(N, SET)                                                           \
    asm volatile("s_waitcnt vmcnt(" #N ")"                                    \
        : "+v"(SET[0]), "+v"(SET[1]), "+v"(SET[2]), "+v"(SET[3]),             \
          "+v"(SET[4]), "+v"(SET[5]), "+v"(SET[6]), "+v"(SET[7]),             \
          "+v"(SET[8]), "+v"(SET[9]));                                        \
    SBAR;

#define PACK10(SET, I0)                                                       \
    {                                                                         \
        _Pragma("unroll")                                                     \
        for (int i = 0; i < 10; ++i) packone(i + (I0), SET[i]);               \
    }

#define WISS(ch, dx, WQ)                                                      \
    {                                                                         \
        const ushort* wb = w1b + (size_t)(ch) * 9216;                         \
        _Pragma("unroll")                                                     \
        for (int dy = 0; dy < 3; ++dy) {                                      \
            _Pragma("unroll")                                                 \
            for (int n = 0; n < 2; ++n) {                                     \
                const ushort* bk = wb + (size_t)((dy * 3 + (dx)) * 2 + n) * 512; \
                asm volatile("global_load_dwordx4 %0, %1, %2"                 \
                             : "=v"(WQ[dy * 2 + n]) : "v"(wvoff), "s"(bk));   \
            }                                                                 \
        }                                                                     \
    }

#define VWW(N, WQ)                                                            \
    asm volatile("s_waitcnt vmcnt(" #N ")"                                    \
        : "+v"(WQ[0]), "+v"(WQ[1]), "+v"(WQ[2]), "+v"(WQ[3]), "+v"(WQ[4]),    \
          "+v"(WQ[5]));                                                       \
    SBAR;

#define COMP_DX(dx, WQ)                                                       \
    {                                                                         \
        const ushort* swp = &sA[w][0];                                        \
        short8 av[10];                                                        \
        _Pragma("unroll")                                                     \
        for (int rr = 0; rr < 10; ++rr)                                       \
            av[rr] = *(const short8*)&swp[(rr * 24 + c_ + (dx) + 3) * 40 + oct * 8]; \
        _Pragma("unroll")                                                     \
        for (int dy = 0; dy < 3; ++dy) {                                      \
            _Pragma("unroll")                                                 \
            for (int m = 0; m < 8; ++m) {                                     \
                acc[m][0] = __builtin_amdgcn_mfma_f32_16x16x32_bf16(          \
                    av[m + dy], WQ[dy * 2 + 0], acc[m][0], 0, 0, 0);          \
                acc[m][1] = __builtin_amdgcn_mfma_f32_16x16x32_bf16(          \
                    av[m + dy], WQ[dy * 2 + 1], acc[m][1], 0, 0, 0);          \
            }                                                                 \
        }                                                                     \
    }

// one full chunk; queue: 20 ->(10) 10+XC=20 ->(10) 10 ->W 16 ->(6) 6 ->W 12
//                        ->(6)dx0 ->W 12 ->(6)dx1 ->(0)dx2
#define CHUNK(ch)                                                             \
    {                                                                         \
        XISS(ch, sa, 0) XISS(ch, sb, 10)                                      \
        VWX(10, sa) PACK10(sa, 0)                                             \
        XISS(ch, sc, 20)                                                      \
        VWX(10, sb) PACK10(sb, 10)                                            \
        WISS(ch, 0, wqA)                                                      \
        VWX(6, sc) PACK10(sc, 20)                                             \
        WISS(ch, 1, wqB)                                                      \
        VWW(6, wqA) COMP_DX(0, wqA)                                           \
        WISS(ch, 2, wqA)                                                      \
        VWW(6, wqB) COMP_DX(1, wqB)                                           \
        VWW(0, wqA) COMP_DX(2, wqA)                                           \
    }

    CHUNK(wu)
    CHUNK(wu + 4)

    // -------- cross-wave ci-reduction (the only barriers in the kernel)
    __syncthreads();
    f32x4* rb = (f32x4*)&sA[0][0];
    if (w > 0) {
        int base = (w - 1) * 1024 + lane;
#pragma unroll
        for (int m = 0; m < 8; ++m)
#pragma unroll
            for (int n = 0; n < 2; ++n)
                rb[base + (m * 2 + n) * 64] = acc[m][n];
    }
    __syncthreads();
    if (w == 0) {
        const float s0 = shift[c_];
        const float s1 = (16 + c_ < CO) ? shift[16 + c_] : 0.f;
#pragma unroll
        for (int m = 0; m < 8; ++m) {
            int gy = y0 + m;
#pragma unroll
            for (int n = 0; n < 2; ++n) {
                f32x4 s = acc[m][n];
#pragma unroll
                for (int v = 1; v < 4; ++v)
                    s += rb[(v - 1) * 1024 + (m * 2 + n) * 64 + lane];
                const float sh = n ? s1 : s0;
                const int co = n * 16 + c_;
                if (co < CO) {
#pragma unroll
                    for (int reg = 0; reg < 4; ++reg) {
                        int gx = x0 + oct * 4 + reg;
                        float* yp = y1 + ((size_t)(b * HH + gy) * WW + gx) * CO;
                        float vv = s[reg] + sh;
                        yp[co] = vv > 0.f ? vv : 0.f;
                    }
                }
            }
        }
    }
}

// ---------------------------------------------------------------------------
// Sampler: thread = (box, k).  Bilinear sample of conv1x1 output = conv1x1 of
// bilinear samples (linear, bias-free).  Mean over k via LDS reduce.
// ---------------------------------------------------------------------------
__global__ __launch_bounds__(224) void sample_k(
    const float* __restrict__ y1, const float* __restrict__ ga,
    const float* __restrict__ w2, float* __restrict__ out)
{
    __shared__ float red[224];
    const int lb  = threadIdx.x / CO;   // local box 0..7
    const int k   = threadIdx.x % CO;   // window index / channel
    const int box = blockIdx.x * 8 + lb;
    const int b   = box >> 11;          // / 2048

    const float* ap = ga + (size_t)box * 7;
    float xg = ap[0], yg = ap[1], wg = ap[3], lg = ap[4], rg = ap[6];
    float c = cosf(rg), s = sinf(rg);

    const int i = k / 7, j = k % 7;
    float xx = ((float)i * (1.f / 3.f) - 0.5f) * wg;
    float yy = ((float)j * (1.f / 6.f) - 0.5f) * lg;
    float xs = (xx * c + yy * s + xg) * 2.5f;
    float ys = (yy * c - xx * s + yg + 40.f) * 2.5f;

    float x0 = floorf(xs), y0 = floorf(ys);
    float wx = xs - x0,    wy = ys - y0;

    float w2r[CO];
    const float* w2p = w2 + k * CO;
#pragma unroll
    for (int q = 0; q < 7; ++q) {
        float4 t = ((const float4*)w2p)[q];
        w2r[4*q] = t.x; w2r[4*q+1] = t.y; w2r[4*q+2] = t.z; w2r[4*q+3] = t.w;
    }

    float val = 0.f;
    const float* yb = y1 + (size_t)b * HH * WW * CO;
#pragma unroll
    for (int cor = 0; cor < 4; ++cor) {
        float yf = y0 + (float)(cor >> 1);
        float xf = x0 + (float)(cor & 1);
        float cw = ((cor & 1) ? wx : 1.f - wx) * ((cor >> 1) ? wy : 1.f - wy);
        if (yf >= 0.f && yf <= (float)(HH - 1) && xf >= 0.f && xf <= (float)(WW - 1)) {
            int yi = (int)yf, xi = (int)xf;
            const float* pp = yb + ((size_t)yi * WW + xi) * CO;
            float d = 0.f;
#pragma unroll
            for (int q = 0; q < 7; ++q) {
                float4 t = ((const float4*)pp)[q];
                d = fmaf(w2r[4*q],   t.x, d);
                d = fmaf(w2r[4*q+1], t.y, d);
                d = fmaf(w2r[4*q+2], t.z, d);
                d = fmaf(w2r[4*q+3], t.w, d);
            }
            val = fmaf(cw, d, val);
        }
    }

    red[threadIdx.x] = val;
    __syncthreads();
    if (k == 0) {
        float sum = 0.f;
#pragma unroll
        for (int q = 0; q < CO; ++q) sum += red[lb * CO + q];
        out[box] = sum * (1.f / 28.f);
    }
}

// ---------------------------------------------------------------------------
extern "C" void kernel_launch(void* const* d_in, const int* in_sizes, int n_in,
                              void* d_out, int out_size, void* d_ws, size_t ws_size,
                              hipStream_t stream) {
    const float* x     = (const float*)d_in[0];
    const float* ga    = (const float*)d_in[1];
    const float* w1    = (const float*)d_in[2];
    const float* gamma = (const float*)d_in[3];
    const float* beta  = (const float*)d_in[4];
    const float* mean  = (const float*)d_in[5];
    const float* var   = (const float*)d_in[6];
    const float* w2    = (const float*)d_in[7];
    float* out = (float*)d_out;

    ushort* w1b   = (ushort*)d_ws;                         // 147456 B
    float*  shift = (float*)((char*)d_ws + 147456);        // 112 B
    float*  y1    = (float*)((char*)d_ws + 147968);        // 4*200*176*28 f32

    prep_k<<<(8 * 9 * 2 * 64 * 8 + 255) / 256, 256, 0, stream>>>(
        w1, gamma, beta, mean, var, w1b, shift);

    conv_mfma_k<<<11 * 25 * 4, 256, 0, stream>>>(x, w1b, shift, y1);

    sample_k<<<(4 * 2048) / 8, 224, 0, stream>>>(y1, ga, w2, out);
}

// Round 15
// 77.389 us; speedup vs baseline: 1.1174x; 1.0918x over previous
//
#include <hip/hip_runtime.h>
#include <hip/hip_bf16.h>

#define HH 200
#define WW 176
#define CIN 256
#define CO 28
#define BN_EPS 1e-3f

typedef __attribute__((ext_vector_type(8))) short short8;
typedef __attribute__((ext_vector_type(4))) float f32x4;

static __device__ __forceinline__ ushort f2bf(float f) {
    __hip_bfloat16 h = __float2bfloat16(f);
    return __builtin_bit_cast(ushort, h);
}

// ---------------------------------------------------------------------------
// prep: w1b chunk-major [h][t][n][lane][j] (bf16, BN-folded), plus shift[28].
//   co = n*16 + (lane&15), ci = h*32 + (lane>>4)*8 + j
// ---------------------------------------------------------------------------
__global__ void prep_k(const float* __restrict__ w1, const float* __restrict__ gamma,
                       const float* __restrict__ beta, const float* __restrict__ mean,
                       const float* __restrict__ var, ushort* __restrict__ w1b,
                       float* __restrict__ shift)
{
    int idx = blockIdx.x * 256 + threadIdx.x;
    if (idx < CO) {
        float sc = gamma[idx] * rsqrtf(var[idx] + BN_EPS);
        shift[idx] = beta[idx] - mean[idx] * sc;
    }
    if (idx < 8 * 9 * 2 * 64 * 8) {
        int j   = idx & 7;
        int l   = (idx >> 3) & 63;
        int n   = (idx >> 9) & 1;
        int rem = idx >> 10;          // h*9 + t
        int t   = rem % 9;
        int h   = rem / 9;
        int co = n * 16 + (l & 15);
        int ci = h * 32 + (l >> 4) * 8 + j;
        float v = 0.f;
        if (co < CO) {
            float sc = gamma[co] * rsqrtf(var[co] + BN_EPS);
            v = w1[(co * CIN + ci) * 9 + t] * sc;
        }
        w1b[idx] = f2bf(v);
    }
}

// ---------------------------------------------------------------------------
// Implicit-GEMM conv3x3 + BN + ReLU, ci-SPLIT across waves (R11 structure).
// Tile 16x8 px. Wave w owns LDS buffer w exclusively and processes ci-chunks
// {w, 4+w} END-TO-END (stage + compute) -> ZERO barriers in the hot path;
// waves drift freely so TLP hides memory latency. R15 change: launch_bounds
// min-waves 2 -> 3 (LDS 49152B allows 3 blocks/CU) => 12 free-running
// waves/CU instead of 8.
// ---------------------------------------------------------------------------
__global__ __launch_bounds__(256, 3) void conv_mfma_k(
    const float* __restrict__ x, const ushort* __restrict__ w1b,
    const float* __restrict__ shift, float* __restrict__ y1)
{
    __shared__ uint4 sbuf[4][768];        // 4 x 12288 B, wave-private

    const int tid  = threadIdx.x;
    const int lane = tid & 63;
    const int w    = tid >> 6;            // wave id
    const int wu   = __builtin_amdgcn_readfirstlane(w);
    const int c_   = lane & 15;
    const int oct  = lane >> 4;

    // XCD-aware bijective block swizzle (1100 blocks, 8 XCDs)
    const int NB = 11 * 25 * 4;
    const int q = NB / 8, r = NB % 8;     // 137, 4
    const int bid  = blockIdx.x;
    const int xcd  = bid & 7;
    const int rank = bid >> 3;
    const int tile = (xcd < r ? xcd * (q + 1) : r * (q + 1) + (xcd - r) * q) + rank;

    const int tx  = tile % 11;
    const int rem = tile / 11;
    const int ty  = rem % 25;
    const int b   = rem / 25;
    const int x0  = tx * 16, y0 = ty * 8;

    const float* xb = x + (size_t)b * CIN * HH * WW;

    // chunk-invariant per-lane staging geometry (halo 18 wide x 10 tall)
    int  soff[3]; bool sval[3];
#pragma unroll
    for (int it = 0; it < 3; ++it) {
        int p = it * 64 + lane;
        int rr = p / 18, cc = p - rr * 18;
        int gy = y0 + rr - 1, gx = x0 + cc - 1;
        bool v = (gy >= 0) & (gy < HH) & (gx >= 0) & (gx < WW);
        sval[it] = v;
        soff[it] = v ? gy * WW + gx : 0;
    }
    const uint voff0 = (uint)(soff[0] * 4);
    const uint voff1 = (uint)(soff[1] * 4);
    const uint voff2 = (uint)(soff[2] * 4);
    const uint wvoff = (uint)(lane * 16);

    float  xA[24], xB[24];
    short8 wqA[6], wqB[6];

    f32x4 acc[8][2];
#pragma unroll
    for (int m = 0; m < 8; ++m)
#pragma unroll
        for (int n = 0; n < 2; ++n)
            acc[m][n] = (f32x4){0.f, 0.f, 0.f, 0.f};

// 24 x-loads for ci-octet o of chunk ch (ch MUST be wave-uniform)
#define ISSUE24(ch, o, XR)                                                    \
    {                                                                         \
        _Pragma("unroll")                                                     \
        for (int j = 0; j < 8; ++j) {                                         \
            const float* bj = xb + (size_t)((ch) * 32 + (o) * 8 + j) * 35200; \
            asm volatile("global_load_dword %0, %1, %2"                       \
                         : "=v"(XR[0 + j]) : "v"(voff0), "s"(bj));            \
            asm volatile("global_load_dword %0, %1, %2"                       \
                         : "=v"(XR[8 + j]) : "v"(voff1), "s"(bj));            \
            asm volatile("global_load_dword %0, %1, %2"                       \
                         : "=v"(XR[16 + j]) : "v"(voff2), "s"(bj));           \
        }                                                                     \
    }

// wait until at most N VMEM outstanding; carry XR[24] as operands
#define WAITX(N, XR)                                                          \
    asm volatile("s_waitcnt vmcnt(" #N ")"                                    \
        : "+v"(XR[0]), "+v"(XR[1]), "+v"(XR[2]), "+v"(XR[3]), "+v"(XR[4]),    \
          "+v"(XR[5]), "+v"(XR[6]), "+v"(XR[7]), "+v"(XR[8]), "+v"(XR[9]),    \
          "+v"(XR[10]), "+v"(XR[11]));                                        \
    asm volatile("s_waitcnt vmcnt(" #N ")"                                    \
        : "+v"(XR[12]), "+v"(XR[13]), "+v"(XR[14]), "+v"(XR[15]),             \
          "+v"(XR[16]), "+v"(XR[17]), "+v"(XR[18]), "+v"(XR[19]),             \
          "+v"(XR[20]), "+v"(XR[21]), "+v"(XR[22]), "+v"(XR[23]));            \
    __builtin_amdgcn_sched_barrier(0);

// convert + pack + ds_write octet o into wave-private buffer
#define PACK(XR, o)                                                           \
    {                                                                         \
        _Pragma("unroll")                                                     \
        for (int it = 0; it < 3; ++it) {                                      \
            int p = it * 64 + lane;                                           \
            ushort u[8];                                                      \
            _Pragma("unroll")                                                 \
            for (int j = 0; j < 8; ++j)                                       \
                u[j] = sval[it] ? f2bf(XR[it * 8 + j]) : (ushort)0;           \
            uint4 val;                                                        \
            val.x = (uint)u[0] | ((uint)u[1] << 16);                          \
            val.y = (uint)u[2] | ((uint)u[3] << 16);                          \
            val.z = (uint)u[4] | ((uint)u[5] << 16);                          \
            val.w = (uint)u[6] | ((uint)u[7] << 16);                          \
            sbuf[w][p * 4 + (((o) + (p >> 1)) & 3)] = val;                    \
        }                                                                     \
    }

// 6 weight-frag loads for column dx of chunk ch (ch wave-uniform)
#define WLOAD6(ch, dx, WQ)                                                    \
    {                                                                         \
        const ushort* wbase = w1b + (size_t)(ch) * 9216;                      \
        _Pragma("unroll")                                                     \
        for (int dy = 0; dy < 3; ++dy) {                                      \
            _Pragma("unroll")                                                 \
            for (int n = 0; n < 2; ++n) {                                     \
                const ushort* bk = wbase + (size_t)((dy * 3 + (dx)) * 2 + n) * 512; \
                asm volatile("global_load_dwordx4 %0, %1, %2"                 \
                             : "=v"(WQ[dy * 2 + n]) : "v"(wvoff), "s"(bk));   \
            }                                                                 \
        }                                                                     \
    }

#define WAITW(N, WQ)                                                          \
    asm volatile("s_waitcnt vmcnt(" #N ")"                                    \
        : "+v"(WQ[0]), "+v"(WQ[1]), "+v"(WQ[2]), "+v"(WQ[3]), "+v"(WQ[4]),    \
          "+v"(WQ[5]));                                                       \
    __builtin_amdgcn_sched_barrier(0);

// 10 A-frag ds_reads + 48 MFMA for column dx
#define COMP_DX(dx, WQ)                                                       \
    {                                                                         \
        short8 av[10];                                                        \
        _Pragma("unroll")                                                     \
        for (int rr = 0; rr < 10; ++rr) {                                     \
            int p = rr * 18 + c_ + (dx);                                      \
            av[rr] = __builtin_bit_cast(short8,                               \
                sbuf[w][p * 4 + ((oct + (p >> 1)) & 3)]);                     \
        }                                                                     \
        _Pragma("unroll")                                                     \
        for (int dy = 0; dy < 3; ++dy) {                                      \
            _Pragma("unroll")                                                 \
            for (int m = 0; m < 8; ++m) {                                     \
                acc[m][0] = __builtin_amdgcn_mfma_f32_16x16x32_bf16(          \
                    av[m + dy], WQ[dy * 2 + 0], acc[m][0], 0, 0, 0);          \
                acc[m][1] = __builtin_amdgcn_mfma_f32_16x16x32_bf16(          \
                    av[m + dy], WQ[dy * 2 + 1], acc[m][1], 0, 0, 0);          \
            }                                                                 \
        }                                                                     \
    }

// stage chunk ch into wave-private buffer (ping-pong octet batches),
// tail pre-issues W(dx=0) into wqA
#define STAGE(ch)                                                             \
    {                                                                         \
        ISSUE24(ch, 0, xA); ISSUE24(ch, 1, xB);                               \
        WAITX(24, xA) PACK(xA, 0);                                            \
        ISSUE24(ch, 2, xA);                                                   \
        WAITX(24, xB) PACK(xB, 1);                                            \
        ISSUE24(ch, 3, xB);                                                   \
        WAITX(24, xA) PACK(xA, 2);                                            \
        WLOAD6(ch, 0, wqA);                                                   \
        WAITX(6, xB) PACK(xB, 3);                                             \
    }

// compute chunk ch (expects W(dx0) in flight in wqA)
#define COMPCH(ch)                                                            \
    {                                                                         \
        WLOAD6(ch, 1, wqB);                                                   \
        WAITW(6, wqA) COMP_DX(0, wqA);                                        \
        WLOAD6(ch, 2, wqA);                                                   \
        WAITW(6, wqB) COMP_DX(1, wqB);                                        \
        WAITW(0, wqA) COMP_DX(2, wqA);                                        \
    }

    STAGE(wu)
    COMPCH(wu)
    STAGE(wu + 4)
    COMPCH(wu + 4)

    // -------- cross-wave ci-reduction (the only barriers in the kernel)
    __syncthreads();                      // all waves done with their sbuf
    f32x4* rb = (f32x4*)&sbuf[0][0];      // 3072 f32x4 slots = 48 KB
    if (w > 0) {
        int base = (w - 1) * 1024 + lane;
#pragma unroll
        for (int m = 0; m < 8; ++m)
#pragma unroll
            for (int n = 0; n < 2; ++n)
                rb[base + (m * 2 + n) * 64] = acc[m][n];
    }
    __syncthreads();
    if (w == 0) {
        const float s0 = shift[c_];
        const float s1 = (16 + c_ < CO) ? shift[16 + c_] : 0.f;
#pragma unroll
        for (int m = 0; m < 8; ++m) {
            int gy = y0 + m;
#pragma unroll
            for (int n = 0; n < 2; ++n) {
                f32x4 s = acc[m][n];
#pragma unroll
                for (int v = 1; v < 4; ++v)
                    s += rb[(v - 1) * 1024 + (m * 2 + n) * 64 + lane];
                const float sh = n ? s1 : s0;
                const int co = n * 16 + c_;
                if (co < CO) {
#pragma unroll
                    for (int reg = 0; reg < 4; ++reg) {
                        int gx = x0 + oct * 4 + reg;
                        float* yp = y1 + ((size_t)(b * HH + gy) * WW + gx) * CO;
                        float vv = s[reg] + sh;
                        yp[co] = vv > 0.f ? vv : 0.f;
                    }
                }
            }
        }
    }
}

// ---------------------------------------------------------------------------
// Sampler: thread = (box, k).  Bilinear sample of conv1x1 output = conv1x1 of
// bilinear samples (linear, bias-free).  Mean over k via LDS reduce.
// ---------------------------------------------------------------------------
__global__ __launch_bounds__(224) void sample_k(
    const float* __restrict__ y1, const float* __restrict__ ga,
    const float* __restrict__ w2, float* __restrict__ out)
{
    __shared__ float red[224];
    const int lb  = threadIdx.x / CO;   // local box 0..7
    const int k   = threadIdx.x % CO;   // window index / channel
    const int box = blockIdx.x * 8 + lb;
    const int b   = box >> 11;          // / 2048

    const float* ap = ga + (size_t)box * 7;
    float xg = ap[0], yg = ap[1], wg = ap[3], lg = ap[4], rg = ap[6];
    float c = cosf(rg), s = sinf(rg);

    const int i = k / 7, j = k % 7;
    float xx = ((float)i * (1.f / 3.f) - 0.5f) * wg;
    float yy = ((float)j * (1.f / 6.f) - 0.5f) * lg;
    float xs = (xx * c + yy * s + xg) * 2.5f;
    float ys = (yy * c - xx * s + yg + 40.f) * 2.5f;

    float x0 = floorf(xs), y0 = floorf(ys);
    float wx = xs - x0,    wy = ys - y0;

    float w2r[CO];
    const float* w2p = w2 + k * CO;
#pragma unroll
    for (int q = 0; q < 7; ++q) {
        float4 t = ((const float4*)w2p)[q];
        w2r[4*q] = t.x; w2r[4*q+1] = t.y; w2r[4*q+2] = t.z; w2r[4*q+3] = t.w;
    }

    float val = 0.f;
    const float* yb = y1 + (size_t)b * HH * WW * CO;
#pragma unroll
    for (int cor = 0; cor < 4; ++cor) {
        float yf = y0 + (float)(cor >> 1);
        float xf = x0 + (float)(cor & 1);
        float cw = ((cor & 1) ? wx : 1.f - wx) * ((cor >> 1) ? wy : 1.f - wy);
        if (yf >= 0.f && yf <= (float)(HH - 1) && xf >= 0.f && xf <= (float)(WW - 1)) {
            int yi = (int)yf, xi = (int)xf;
            const float* p = yb + ((size_t)yi * WW + xi) * CO;
            float d = 0.f;
#pragma unroll
            for (int q = 0; q < 7; ++q) {
                float4 t = ((const float4*)p)[q];
                d = fmaf(w2r[4*q],   t.x, d);
                d = fmaf(w2r[4*q+1], t.y, d);
                d = fmaf(w2r[4*q+2], t.z, d);
                d = fmaf(w2r[4*q+3], t.w, d);
            }
            val = fmaf(cw, d, val);
        }
    }

    red[threadIdx.x] = val;
    __syncthreads();
    if (k == 0) {
        float sum = 0.f;
#pragma unroll
        for (int q = 0; q < CO; ++q) sum += red[lb * CO + q];
        out[box] = sum * (1.f / 28.f);
    }
}

// ---------------------------------------------------------------------------
extern "C" void kernel_launch(void* const* d_in, const int* in_sizes, int n_in,
                              void* d_out, int out_size, void* d_ws, size_t ws_size,
                              hipStream_t stream) {
    const float* x     = (const float*)d_in[0];
    const float* ga    = (const float*)d_in[1];
    const float* w1    = (const float*)d_in[2];
    const float* gamma = (const float*)d_in[3];
    const float* beta  = (const float*)d_in[4];
    const float* mean  = (const float*)d_in[5];
    const float* var   = (const float*)d_in[6];
    const float* w2    = (const float*)d_in[7];
    float* out = (float*)d_out;

    ushort* w1b   = (ushort*)d_ws;                         // 147456 B
    float*  shift = (float*)((char*)d_ws + 147456);        // 112 B
    float*  y1    = (float*)((char*)d_ws + 147968);        // 4*200*176*28 f32

    prep_k<<<(8 * 9 * 2 * 64 * 8 + 255) / 256, 256, 0, stream>>>(
        w1, gamma, beta, mean, var, w1b, shift);

    conv_mfma_k<<<11 * 25 * 4, 256, 0, stream>>>(x, w1b, shift, y1);

    sample_k<<<(4 * 2048) / 8, 224, 0, stream>>>(y1, ga, w2, out);
}